// Round 2
// baseline (213.992 us; speedup 1.0000x reference)
//
#include <hip/hip_runtime.h>
#include <cstdint>

// ConvBnA int8-in-int32 conv via bf16 MFMA (exact: |acc| < 2^24).
// Pass 1a: weight int32 [co][ci][3][3] -> bf16 [kh*3+kw][co][ci]  (+ zero page)
// Pass 1b: x int32 NCHW -> bf16 NHWC (per-n transpose [128][3136] -> [3136][128])
// Pass 2 : implicit GEMM, M=256 (co), N=100352 (pixels), K=9*128.
//          128x128 block tile, BK=64, 4 waves (2x2), 16x16x32 bf16 MFMA,
//          double-buffered LDS, global_load_lds width=16, counted vmcnt(8),
//          XOR chunk-swizzle (source-permuted, read-XOR).
// Output: harness reads integer outputs as int32 -> store int, not float.

typedef __attribute__((ext_vector_type(8))) short short8;
typedef __attribute__((ext_vector_type(4))) float f32x4;

#define C_IN   128
#define C_OUT  256
#define HW2    3136      // 56*56
#define NPIX   100352    // 32*3136
#define OUT_NSTRIDE 802816  // 256*3136

// workspace layout (bytes)
#define XBF_BYTES 25690112           // 12845056 bf16
#define WBF_OFF   25690112
#define WBF_BYTES 589824             // 9*256*128 bf16
#define ZP_OFF    (WBF_OFF + WBF_BYTES)   // 256 zero bytes

__device__ __forceinline__ ushort f2bf(float f) {
  return (ushort)(__builtin_bit_cast(unsigned int, f) >> 16);  // exact for our ints
}

__device__ __forceinline__ void gload_lds16(const void* g, void* l) {
  __builtin_amdgcn_global_load_lds(
      (const __attribute__((address_space(1))) void*)(uintptr_t)g,
      (__attribute__((address_space(3))) void*)(uint32_t)(uintptr_t)l,
      16, 0, 0);
}

// ---------------- pass 1a: weight transform + zero page ----------------
__global__ void wxform(const int* __restrict__ w, ushort* __restrict__ wbf,
                       float* __restrict__ zp) {
  int id = blockIdx.x * 256 + threadIdx.x;      // over 9*256*128 = 294912
  int ci  = id & 127;
  int co  = (id >> 7) & 255;
  int kwh = id >> 15;                           // kh*3+kw
  int v = w[co * 1152 + ci * 9 + kwh];
  wbf[id] = f2bf((float)v);
  if (blockIdx.x == 0 && threadIdx.x < 64) zp[threadIdx.x] = 0.0f;
}

// ---------------- pass 1b: x NCHW int32 -> NHWC bf16 ----------------
__global__ __launch_bounds__(256) void xform(const int* __restrict__ x,
                                             ushort* __restrict__ xbf) {
  __shared__ ushort t[64][65];
  int bid = blockIdx.x;                 // 32 * 2 * 49 = 3136 blocks
  int hb = bid % 49;
  int tmp = bid / 49;
  int cb = tmp & 1;
  int n  = tmp >> 1;
  int tid = threadIdx.x;
  int c  = tid & 63;
  int r0 = tid >> 6;
  const int* src = x + n * (C_IN * HW2) + (cb * 64) * HW2 + hb * 64;
#pragma unroll
  for (int i = 0; i < 16; i++) {
    int r = r0 + i * 4;
    t[r][c] = f2bf((float)src[r * HW2 + c]);   // coalesced 256B over c
  }
  __syncthreads();
  ushort* dst = xbf + n * (HW2 * C_IN) + (hb * 64) * C_IN + cb * 64;
#pragma unroll
  for (int i = 0; i < 16; i++) {
    int hwi = r0 + i * 4;
    dst[hwi * C_IN + c] = t[c][hwi];           // coalesced 128B over c (=ci)
  }
}

// ---------------- pass 2: MFMA implicit GEMM ----------------
__global__ __launch_bounds__(256, 2) void conv_mfma(
    const ushort* __restrict__ xbf, const ushort* __restrict__ wbf,
    const ushort* __restrict__ zp,
    const int* __restrict__ nshift, const int* __restrict__ tbias,
    const int* __restrict__ aminp, const int* __restrict__ amaxp,
    int* __restrict__ out) {
  __shared__ char lds[65536];   // 2 bufs x (A 16KB + B 16KB)

  const int tid = threadIdx.x;
  const int bid = blockIdx.x;
  const int bm = bid & 1;        // co block (0..1)
  const int pb = bid >> 1;       // pixel block (0..783)
  const int l  = tid & 63;
  const int wid = tid >> 6;
  const int wm = wid >> 1, wn = wid & 1;   // 2x2 waves, 64x64 each

  // ---- staging constants ----
  // slot j = tid + i*256 ; row = j>>3 (0..127), local chunk = j&7 (16B units)
  // swizzle: data for global chunk (chl ^ (row&7)) is stored at local chunk chl
  const int chl = tid & 7;
  const int rsw = (tid >> 3) & 7;          // (row & 7), invariant in i
  const int chg = chl ^ rsw;               // global chunk to fetch
  const int koff_sw = chg * 8;             // element offset (x8 bf16 per chunk)

  // pixels this thread stages (4 of them, fixed across K-loop)
  int p_idx[4], p_h[4], p_w[4];
#pragma unroll
  for (int i = 0; i < 4; i++) {
    int pr = (tid >> 3) + i * 32;
    int p  = pb * 128 + pr;
    int n  = p / HW2;
    int hw = p - n * HW2;
    int h  = hw / 56;
    int w  = hw - h * 56;
    p_idx[i] = p; p_h[i] = h; p_w[i] = w;
  }

  auto stageAB = [&](int g, int kt, int buf) {
    char* Ab = lds + buf * 32768;
    char* Bb = Ab + 16384;
    const int dh = g / 3 - 1, dw = g % 3 - 1;
    const int doff = dh * 56 + dw;
    const int kbase = kt * 64 + koff_sw;
    // A: weight tile [co 128][ci 64]
    const ushort* wsrc = wbf + (g * 256 + bm * 128) * 128 + kbase;
#pragma unroll
    for (int i = 0; i < 4; i++) {
      int row = (tid >> 3) + i * 32;
      gload_lds16(wsrc + row * 128, Ab + (tid + i * 256) * 16);
    }
    // B: x tile [pix 128][ci 64], zero-page redirect for halo
#pragma unroll
    for (int i = 0; i < 4; i++) {
      int h2 = p_h[i] + dh, w2 = p_w[i] + dw;
      bool valid = ((unsigned)h2 < 56u) && ((unsigned)w2 < 56u);
      const ushort* gp = valid ? (xbf + (p_idx[i] + doff) * 128 + kbase)
                               : (const ushort*)zp;
      gload_lds16(gp, Bb + (tid + i * 256) * 16);
    }
  };

  f32x4 acc[4][4] = {};
  const int lrow = l & 15;
  const int lk16 = (l >> 4) * 16;          // byte offset of lane's k-chunk
  const int lsw  = (l & 7) << 4;           // read-side swizzle XOR

  auto computeStep = [&](int buf) {
    char* Ab = lds + buf * 32768;
    char* Bb = Ab + 16384;
#pragma unroll
    for (int kk = 0; kk < 2; kk++) {
      short8 a[4], b[4];
      const int cb = ((kk * 64 + lk16) ^ lsw);
#pragma unroll
      for (int mi = 0; mi < 4; mi++) {
        int row = wm * 64 + mi * 16 + lrow;
        a[mi] = *(const short8*)(Ab + row * 128 + cb);
      }
#pragma unroll
      for (int ni = 0; ni < 4; ni++) {
        int row = wn * 64 + ni * 16 + lrow;
        b[ni] = *(const short8*)(Bb + row * 128 + cb);
      }
#pragma unroll
      for (int mi = 0; mi < 4; mi++)
#pragma unroll
        for (int ni = 0; ni < 4; ni++)
          acc[mi][ni] = __builtin_amdgcn_mfma_f32_16x16x32_bf16(
              a[mi], b[ni], acc[mi][ni], 0, 0, 0);
    }
  };

  stageAB(0, 0, 0);
#pragma unroll 1
  for (int s = 0; s < 18; ++s) {          // 9 taps x 2 k-halves
    const int s1 = s + 1;
    if (s1 < 18) stageAB(s1 >> 1, s1 & 1, s1 & 1);
    __builtin_amdgcn_sched_barrier(0);
    if (s1 < 18) { asm volatile("s_waitcnt vmcnt(8)" ::: "memory"); }
    else         { asm volatile("s_waitcnt vmcnt(0)" ::: "memory"); }
    __builtin_amdgcn_s_barrier();
    __builtin_amdgcn_sched_barrier(0);
    computeStep(s & 1);
    __builtin_amdgcn_sched_barrier(0);
    __builtin_amdgcn_s_barrier();
    __builtin_amdgcn_sched_barrier(0);
  }

  // ---- epilogue: +t, >> (-n), clamp, store as int32 ----
  const int amin = aminp[0], amax = amaxp[0];
  int pbase[4];
#pragma unroll
  for (int ni = 0; ni < 4; ni++) {
    int p = pb * 128 + wn * 64 + ni * 16 + lrow;
    int n = p / HW2;
    int hw = p - n * HW2;
    pbase[ni] = n * OUT_NSTRIDE + hw;
  }
#pragma unroll
  for (int mi = 0; mi < 4; mi++) {
    int co0 = bm * 128 + wm * 64 + mi * 16 + ((l >> 4) << 2);
    const int4 t4 = *(const int4*)(tbias + co0);
    const int4 n4 = *(const int4*)(nshift + co0);
#pragma unroll
    for (int ni = 0; ni < 4; ni++) {
      f32x4 fr = acc[mi][ni];
#pragma unroll
      for (int r = 0; r < 4; r++) {
        int tv = (r == 0) ? t4.x : (r == 1) ? t4.y : (r == 2) ? t4.z : t4.w;
        int nv = (r == 0) ? n4.x : (r == 1) ? n4.y : (r == 2) ? n4.z : n4.w;
        int v = (int)fr[r] + tv;
        v = v >> (-nv);                       // arithmetic shift, n = -8
        v = v < amin ? amin : (v > amax ? amax : v);
        out[pbase[ni] + (co0 + r) * HW2] = v;
      }
    }
  }
}

extern "C" void kernel_launch(void* const* d_in, const int* in_sizes, int n_in,
                              void* d_out, int out_size, void* d_ws, size_t ws_size,
                              hipStream_t stream) {
  const int* x      = (const int*)d_in[0];
  const int* w      = (const int*)d_in[1];
  const int* nshift = (const int*)d_in[2];
  const int* tbias  = (const int*)d_in[3];
  const int* aminp  = (const int*)d_in[4];
  const int* amaxp  = (const int*)d_in[5];
  int* out = (int*)d_out;

  ushort* xbf = (ushort*)d_ws;
  ushort* wbf = (ushort*)((char*)d_ws + WBF_OFF);
  ushort* zp  = (ushort*)((char*)d_ws + ZP_OFF);

  hipLaunchKernelGGL(wxform, dim3(1152), dim3(256), 0, stream, w, wbf, (float*)zp);
  hipLaunchKernelGGL(xform,  dim3(3136), dim3(256), 0, stream, x, xbf);
  hipLaunchKernelGGL(conv_mfma, dim3(1568), dim3(256), 0, stream,
                     xbf, wbf, zp, nshift, tbias, aminp, amaxp, out);
}

// Round 3
// 186.002 us; speedup vs baseline: 1.1505x; 1.1505x over previous
//
#include <hip/hip_runtime.h>
#include <cstdint>

// ConvBnA int8 conv via i8 MFMA (exact: i32 accumulation).
// Pass 1a: weight int32 [co][ci][3][3] -> int8 [kh*3+kw][co][ci] (+ zero page)
// Pass 1b: x int32 NCHW -> int8 NHWC, register-only transpose (no LDS)
// Pass 2 : implicit GEMM, M=256 (co), N=100352 (pix), K=9*128, BK=128/tap.
//          128x128 tile, 4 waves, 16x16x64 i8 MFMA, double-buffered LDS,
//          global_load_lds width=16, counted vmcnt(8), XOR chunk-swizzle.
//          Byte-geometry identical to the verified bf16 kernel (128B rows).
// Output: harness reads integer outputs as int32 -> store int.

typedef __attribute__((ext_vector_type(4))) int i32x4;
typedef __attribute__((ext_vector_type(2))) int i32x2;

#define C_IN   128
#define C_OUT  256
#define HW2    3136      // 56*56
#define OUT_NSTRIDE 802816  // 256*3136

// workspace layout (bytes)
#define XQ_BYTES 12845056            // 100352 * 128 int8
#define WQ_OFF   XQ_BYTES
#define WQ_BYTES 294912              // 9*256*128 int8
#define ZP_OFF   (WQ_OFF + WQ_BYTES) // 256 zero bytes (16B-aligned)

__device__ __forceinline__ void gload_lds16(const void* g, void* l) {
  __builtin_amdgcn_global_load_lds(
      (const __attribute__((address_space(1))) void*)(uintptr_t)g,
      (__attribute__((address_space(3))) void*)(uint32_t)(uintptr_t)l,
      16, 0, 0);
}

// ---------------- pass 1a: weight -> int8 [g][co][ci] + zero page ----------------
__global__ void wxform(const int* __restrict__ w, char* __restrict__ wq,
                       int* __restrict__ zp) {
  int id = blockIdx.x * 256 + threadIdx.x;      // over 9*256*128 = 294912
  int ci = id & 127;
  int co = (id >> 7) & 255;
  int g  = id >> 15;                            // kh*3+kw
  wq[id] = (char)w[co * 1152 + ci * 9 + g];
  if (blockIdx.x == 0 && threadIdx.x < 64) zp[threadIdx.x] = 0;
}

// ---------------- pass 1b: x NCHW int32 -> NHWC int8, reg-only transpose ----------------
__global__ __launch_bounds__(256) void xform(const int* __restrict__ x,
                                             char* __restrict__ xq) {
  int bid = blockIdx.x;                 // 32n * 49hb = 1568 blocks
  int hb = bid % 49;
  int n  = bid / 49;
  int t  = threadIdx.x;
  int cig = t & 15;                     // ci group (8 ci each)
  int hw0 = (t >> 4) * 4;               // 4 pixels
  const int* src = x + n * (C_IN * HW2) + hb * 64 + hw0;
  i32x4 ld[8];
#pragma unroll
  for (int j = 0; j < 8; j++)
    ld[j] = *(const i32x4*)(src + (cig * 8 + j) * HW2);   // 16B, 4 lanes -> 64B sector
  char* dst = xq + (size_t)(n * HW2 + hb * 64 + hw0) * 128 + cig * 8;
#pragma unroll
  for (int p = 0; p < 4; p++) {
    unsigned lo = (ld[0][p] & 255) | ((ld[1][p] & 255) << 8) |
                  ((ld[2][p] & 255) << 16) | ((unsigned)(ld[3][p] & 255) << 24);
    unsigned hi = (ld[4][p] & 255) | ((ld[5][p] & 255) << 8) |
                  ((ld[6][p] & 255) << 16) | ((unsigned)(ld[7][p] & 255) << 24);
    i32x2 v; v[0] = (int)lo; v[1] = (int)hi;
    *(i32x2*)(dst + p * 128) = v;       // 8B, 16 lanes -> 128B row contiguous
  }
}

// ---------------- pass 2: i8 MFMA implicit GEMM ----------------
__global__ __launch_bounds__(256, 2) void conv_mfma(
    const char* __restrict__ xq, const char* __restrict__ wq,
    const char* __restrict__ zp,
    const int* __restrict__ nshift, const int* __restrict__ tbias,
    const int* __restrict__ aminp, const int* __restrict__ amaxp,
    int* __restrict__ out) {
  __shared__ char lds[65536];   // 2 bufs x (A 16KB + B 16KB); row = 128B (128 ci int8)

  const int tid = threadIdx.x;
  const int bid = blockIdx.x;
  const int bm = bid & 1;        // co block (0..1)
  const int pb = bid >> 1;       // pixel block (0..783)
  const int l  = tid & 63;
  const int wid = tid >> 6;
  const int wm = wid >> 1, wn = wid & 1;   // 2x2 waves, 64x64 each

  // staging: slot j = tid + i*256; row = j>>3 (0..127), local chunk = j&7 (16B)
  // swizzle: local chunk chl holds global chunk chl ^ (row&7)
  const int chl = tid & 7;
  const int rsw = (tid >> 3) & 7;          // row&7, invariant in i (i*32)
  const int chg = chl ^ rsw;
  const int kboff = chg * 16;              // byte offset within 128B row

  int p_idx[4], p_h[4], p_w[4];
#pragma unroll
  for (int i = 0; i < 4; i++) {
    int pr = (tid >> 3) + i * 32;
    int p  = pb * 128 + pr;
    int n  = p / HW2;
    int hw = p - n * HW2;
    int h  = hw / 56;
    int w  = hw - h * 56;
    p_idx[i] = p; p_h[i] = h; p_w[i] = w;
  }

  auto stageAB = [&](int g, int buf) {
    char* Ab = lds + buf * 32768;
    char* Bb = Ab + 16384;
    const int dh = g / 3 - 1, dw = g % 3 - 1;
    const int doff = dh * 56 + dw;
    // A: weight tile [co 128][ci 128] int8
    const char* wsrc = wq + (((g * 256 + bm * 128)) << 7) + kboff;
#pragma unroll
    for (int i = 0; i < 4; i++) {
      int row = (tid >> 3) + i * 32;
      gload_lds16(wsrc + (row << 7), Ab + (tid + i * 256) * 16);
    }
    // B: x tile [pix 128][ci 128] int8, zero-page redirect for halo
#pragma unroll
    for (int i = 0; i < 4; i++) {
      int h2 = p_h[i] + dh, w2 = p_w[i] + dw;
      bool valid = ((unsigned)h2 < 56u) && ((unsigned)w2 < 56u);
      const char* gp = valid ? (xq + ((size_t)(p_idx[i] + doff) << 7) + kboff)
                             : zp;
      gload_lds16(gp, Bb + (tid + i * 256) * 16);
    }
  };

  i32x4 acc[4][4] = {};
  const int lrow = l & 15;
  const int lk   = (l >> 4) * 16;          // byte offset of lane's k-chunk
  const int lsw  = (l & 7) << 4;           // read-side swizzle XOR (row&7 == l&7)

  auto computeStep = [&](int buf) {
    char* Ab = lds + buf * 32768;
    char* Bb = Ab + 16384;
#pragma unroll
    for (int kk = 0; kk < 2; kk++) {       // K=128 per tap = 2 x K64 MFMA
      i32x4 a[4], b[4];
      const int cb = ((kk * 64 + lk) ^ lsw);
#pragma unroll
      for (int mi = 0; mi < 4; mi++) {
        int row = wm * 64 + mi * 16 + lrow;
        a[mi] = *(const i32x4*)(Ab + (row << 7) + cb);
      }
#pragma unroll
      for (int ni = 0; ni < 4; ni++) {
        int row = wn * 64 + ni * 16 + lrow;
        b[ni] = *(const i32x4*)(Bb + (row << 7) + cb);
      }
#pragma unroll
      for (int mi = 0; mi < 4; mi++)
#pragma unroll
        for (int ni = 0; ni < 4; ni++)
          acc[mi][ni] = __builtin_amdgcn_mfma_i32_16x16x64_i8(
              a[mi], b[ni], acc[mi][ni], 0, 0, 0);
    }
  };

  stageAB(0, 0);
#pragma unroll 1
  for (int s = 0; s < 9; ++s) {           // 9 taps, BK=128 each
    const int s1 = s + 1;
    if (s1 < 9) stageAB(s1, s1 & 1);
    __builtin_amdgcn_sched_barrier(0);
    if (s1 < 9) { asm volatile("s_waitcnt vmcnt(8)" ::: "memory"); }
    else        { asm volatile("s_waitcnt vmcnt(0)" ::: "memory"); }
    __builtin_amdgcn_s_barrier();
    __builtin_amdgcn_sched_barrier(0);
    computeStep(s & 1);
    __builtin_amdgcn_sched_barrier(0);
    __builtin_amdgcn_s_barrier();
    __builtin_amdgcn_sched_barrier(0);
  }

  // ---- epilogue: +t, >> (-n), clamp, store int32 (all-integer now) ----
  const int amin = aminp[0], amax = amaxp[0];
  int pbase[4];
#pragma unroll
  for (int ni = 0; ni < 4; ni++) {
    int p = pb * 128 + wn * 64 + ni * 16 + lrow;
    int n = p / HW2;
    int hw = p - n * HW2;
    pbase[ni] = n * OUT_NSTRIDE + hw;
  }
#pragma unroll
  for (int mi = 0; mi < 4; mi++) {
    int co0 = bm * 128 + wm * 64 + mi * 16 + ((l >> 4) << 2);
    const int4 t4 = *(const int4*)(tbias + co0);
    const int4 n4 = *(const int4*)(nshift + co0);
#pragma unroll
    for (int ni = 0; ni < 4; ni++) {
#pragma unroll
      for (int r = 0; r < 4; r++) {
        int tv = (r == 0) ? t4.x : (r == 1) ? t4.y : (r == 2) ? t4.z : t4.w;
        int nv = (r == 0) ? n4.x : (r == 1) ? n4.y : (r == 2) ? n4.z : n4.w;
        int v = acc[mi][ni][r] + tv;
        v = v >> (-nv);                       // arithmetic shift
        v = v < amin ? amin : (v > amax ? amax : v);
        out[pbase[ni] + (co0 + r) * HW2] = v;
      }
    }
  }
}

extern "C" void kernel_launch(void* const* d_in, const int* in_sizes, int n_in,
                              void* d_out, int out_size, void* d_ws, size_t ws_size,
                              hipStream_t stream) {
  const int* x      = (const int*)d_in[0];
  const int* w      = (const int*)d_in[1];
  const int* nshift = (const int*)d_in[2];
  const int* tbias  = (const int*)d_in[3];
  const int* aminp  = (const int*)d_in[4];
  const int* amaxp  = (const int*)d_in[5];
  int* out = (int*)d_out;

  char* xq = (char*)d_ws;
  char* wq = (char*)d_ws + WQ_OFF;
  char* zp = (char*)d_ws + ZP_OFF;

  hipLaunchKernelGGL(wxform, dim3(1152), dim3(256), 0, stream, w, wq, (int*)zp);
  hipLaunchKernelGGL(xform,  dim3(1568), dim3(256), 0, stream, x, xq);
  hipLaunchKernelGGL(conv_mfma, dim3(1568), dim3(256), 0, stream,
                     xq, wq, zp, nshift, tbias, aminp, amaxp, out);
}